// Round 2
// baseline (570.505 us; speedup 1.0000x reference)
//
#include <hip/hip_runtime.h>
#include <cstdint>

#define N_TOT 1572864
#define KSEL 4096
#define CAP 8192
#define BINS 4096
#define SCORE_THR 0.5f
#define IOU_THR 0.1f

// ---------------- init: zero hist/counters/sorted arrays ----------------
__global__ void k_init(uint32_t* hist, uint32_t* ctrs, uint32_t* order, float* topScore) {
    int i = blockIdx.x * blockDim.x + threadIdx.x;
    if (i < BINS) hist[i] = 0;
    if (i < 16) ctrs[i] = 0;
    if (i < KSEL) { order[i] = 0; topScore[i] = 0.0f; }
}

// ---------------- histogram over score bits (scores in (0.5,1)) ----------------
__global__ void k_hist(const float2* __restrict__ cls2, uint32_t* __restrict__ hist) {
    int i = blockIdx.x * blockDim.x + threadIdx.x;
    int stride = gridDim.x * blockDim.x;
    for (; i < N_TOT; i += stride) {
        float s = cls2[i].y;
        if (s > SCORE_THR) {
            uint32_t b = __float_as_uint(s);
            uint32_t bin = (b - 0x3F000000u) >> 11;
            if (bin >= BINS) bin = BINS - 1;
            atomicAdd(&hist[bin], 1u);
        }
    }
}

// ---------------- find cutoff bin T: largest b with suffix(b) >= K ----------------
__global__ void k_thresh(const uint32_t* __restrict__ hist, uint32_t* __restrict__ ctrs) {
    __shared__ uint32_t s_suf[1024];
    int t = threadIdx.x;
    uint32_t l0 = hist[t*4+0], l1 = hist[t*4+1], l2 = hist[t*4+2], l3 = hist[t*4+3];
    s_suf[t] = l0 + l1 + l2 + l3;
    __syncthreads();
    for (int off = 1; off < 1024; off <<= 1) {
        uint32_t v = (t + off < 1024) ? s_suf[t + off] : 0u;
        __syncthreads();
        s_suf[t] += v;
        __syncthreads();
    }
    uint32_t snext = (t < 1023) ? s_suf[t + 1] : 0u;
    uint32_t suf3 = snext + l3;
    uint32_t suf2 = suf3 + l2;
    uint32_t suf1 = suf2 + l1;
    uint32_t suf0 = suf1 + l0;
    uint32_t sufs[5] = {suf0, suf1, suf2, suf3, snext};
    #pragma unroll
    for (int q = 0; q < 4; q++) {
        if (sufs[q] >= KSEL && sufs[q+1] < KSEL) ctrs[1] = (uint32_t)(t*4 + q);
    }
    if (t == 0 && s_suf[0] < KSEL) ctrs[1] = 0;  // fewer than K candidates
}

// ---------------- gather candidates with bin >= T as sortable 64-bit keys ----------------
__global__ void k_gather(const float2* __restrict__ cls2, uint32_t* __restrict__ ctrs,
                         uint64_t* __restrict__ keys) {
    uint32_t T = ctrs[1];
    uint32_t basebits = 0x3F000000u + (T << 11);
    int i = blockIdx.x * blockDim.x + threadIdx.x;
    int stride = gridDim.x * blockDim.x;
    for (; i < N_TOT; i += stride) {
        float s = cls2[i].y;
        if (s > SCORE_THR) {
            uint32_t b = __float_as_uint(s);
            if (b >= basebits) {
                uint32_t pos = atomicAdd(&ctrs[0], 1u);
                if (pos < CAP) keys[pos] = ((uint64_t)b << 32) | (uint32_t)(~(uint32_t)i);
            }
        }
    }
}

// ---------------- exact rank sort (score desc, idx asc); keys are unique ----------------
__global__ void k_rank(const uint64_t* __restrict__ keys, const uint32_t* __restrict__ ctrs,
                       uint32_t* __restrict__ order, float* __restrict__ topScore) {
    __shared__ uint64_t s_keys[256];
    uint32_t M = ctrs[0]; if (M > CAP) M = CAP;
    int j = blockIdx.x * blockDim.x + threadIdx.x;
    uint64_t myKey = (j < (int)M) ? keys[j] : 0ull;
    uint32_t rank = 0;
    for (uint32_t base = 0; base < M; base += 256) {
        uint32_t idx = base + threadIdx.x;
        s_keys[threadIdx.x] = (idx < M) ? keys[idx] : 0ull;
        __syncthreads();
        uint32_t lim = min(256u, M - base);
        for (uint32_t q = 0; q < lim; q++)
            rank += (s_keys[q] > myKey) ? 1u : 0u;
        __syncthreads();
    }
    if (j < (int)M && rank < KSEL) {
        uint32_t bits = (uint32_t)(myKey >> 32);
        uint32_t srcIdx = ~((uint32_t)(myKey & 0xFFFFFFFFull));
        order[rank] = srcIdx;
        topScore[rank] = __uint_as_float(bits);
    }
}

// ---------------- decode+clip the K winners (mimic numpy f32 rounding; no FMA) ----------------
__global__ void k_decode(const float* __restrict__ anchors, const float* __restrict__ reg,
                         const uint32_t* __restrict__ order, float* __restrict__ boxes,
                         float* __restrict__ areas) {
    int k = blockIdx.x * blockDim.x + threadIdx.x;
    if (k >= KSEL) return;
    uint32_t idx = order[k];
    float a0 = anchors[idx*4+0], a1 = anchors[idx*4+1], a2 = anchors[idx*4+2], a3 = anchors[idx*4+3];
    float d0 = __fmul_rn(reg[idx*4+0], 0.1f);
    float d1 = __fmul_rn(reg[idx*4+1], 0.1f);
    float d2 = __fmul_rn(reg[idx*4+2], 0.2f);
    float d3 = __fmul_rn(reg[idx*4+3], 0.2f);
    float w  = __fsub_rn(a2, a0);
    float h  = __fsub_rn(a3, a1);
    float cx = __fadd_rn(a0, __fmul_rn(0.5f, w));
    float cy = __fadd_rn(a1, __fmul_rn(0.5f, h));
    float pcx = __fadd_rn(cx, __fmul_rn(d0, w));
    float pcy = __fadd_rn(cy, __fmul_rn(d1, h));
    float pw = __fmul_rn((float)exp((double)d2), w);
    float ph = __fmul_rn((float)exp((double)d3), h);
    float x0 = __fsub_rn(pcx, __fmul_rn(0.5f, pw));
    float y0 = __fsub_rn(pcy, __fmul_rn(0.5f, ph));
    float x1 = __fadd_rn(pcx, __fmul_rn(0.5f, pw));
    float y1 = __fadd_rn(pcy, __fmul_rn(0.5f, ph));
    x0 = fminf(fmaxf(x0, 0.0f), 1024.0f);
    y0 = fminf(fmaxf(y0, 0.0f), 1024.0f);
    x1 = fminf(fmaxf(x1, 0.0f), 1024.0f);
    y1 = fminf(fmaxf(y1, 0.0f), 1024.0f);
    boxes[k*4+0] = x0; boxes[k*4+1] = y0; boxes[k*4+2] = x1; boxes[k*4+3] = y1;
    areas[k] = __fmul_rn(__fsub_rn(x1, x0), __fsub_rn(y1, y0));
}

// ---------------- pairwise suppression bitmask (upper-triangle 64x64 blocks) ----------------
__global__ void k_mask(const float* __restrict__ boxes, const float* __restrict__ areas,
                       unsigned long long* __restrict__ rowmask) {
    int bi = blockIdx.y, bj = blockIdx.x;
    if (bj < bi) return;  // j>i never true there; reduce skips those words
    __shared__ float s_box[64][4];
    __shared__ float s_area[64];
    int t = threadIdx.x;
    int r0 = bi*64 + t;
    s_box[t][0] = boxes[r0*4+0];
    s_box[t][1] = boxes[r0*4+1];
    s_box[t][2] = boxes[r0*4+2];
    s_box[t][3] = boxes[r0*4+3];
    s_area[t] = areas[r0];
    __syncthreads();
    int j = bj*64 + t;
    float jx0 = boxes[j*4+0], jy0 = boxes[j*4+1], jx1 = boxes[j*4+2], jy1 = boxes[j*4+3];
    float ja = areas[j];
    unsigned long long myword = 0ull;
    #pragma unroll 4
    for (int r = 0; r < 64; r++) {
        int i = bi*64 + r;
        float w = __fsub_rn(fminf(s_box[r][2], jx1), fmaxf(s_box[r][0], jx0));
        float h = __fsub_rn(fminf(s_box[r][3], jy1), fmaxf(s_box[r][1], jy0));
        w = fmaxf(w, 0.0f); h = fmaxf(h, 0.0f);
        float inter = __fmul_rn(w, h);
        float denom = __fadd_rn(__fsub_rn(__fadd_rn(s_area[r], ja), inter), 1e-8f);
        float iou = __fdiv_rn(inter, denom);
        bool sup = (iou > IOU_THR) && (j > i);
        unsigned long long b = __ballot(sup);
        if (t == r) myword = b;
    }
    rowmask[(unsigned long long)(bi*64 + t)*64 + bj] = myword;
}

// ---------------- sequential greedy NMS reduce (single wave, lane w owns word w) ----------------
__global__ void k_reduce(const float* __restrict__ topScore,
                         const unsigned long long* __restrict__ rowmask,
                         unsigned long long* __restrict__ keepWords) {
    int w = threadIdx.x;  // 0..63
    unsigned long long keep = 0ull;
    for (int c = 0; c < 64; c++) {
        if (topScore[w*64 + c] > 0.0f) keep |= (1ull << c);
    }
    unsigned long long nextrow = rowmask[w];
    for (int i = 0; i < KSEL; i++) {
        unsigned long long row = nextrow;
        if (i + 1 < KSEL) nextrow = rowmask[(unsigned long long)(i+1)*64 + w];
        unsigned long long kw = __shfl(keep, i >> 6);
        if ((kw >> (i & 63)) & 1ull) {
            if (w >= (i >> 6)) keep &= ~row;   // lower words never written/needed
        }
    }
    keepWords[w] = keep;
}

// ---------------- final output: boxes*scale*keep, score*keep ----------------
__global__ void k_out(const float* __restrict__ boxes, const float* __restrict__ topScore,
                      const unsigned long long* __restrict__ keepWords,
                      const int* __restrict__ Hp, const int* __restrict__ Wp,
                      float* __restrict__ out) {
    int k = blockIdx.x * blockDim.x + threadIdx.x;
    if (k >= KSEL) return;
    float sx = (float)((double)Wp[0] / 1024.0);
    float sy = (float)((double)Hp[0] / 1024.0);
    float f = ((keepWords[k >> 6] >> (k & 63)) & 1ull) ? 1.0f : 0.0f;
    out[k*5+0] = __fmul_rn(__fmul_rn(boxes[k*4+0], sx), f);
    out[k*5+1] = __fmul_rn(__fmul_rn(boxes[k*4+1], sy), f);
    out[k*5+2] = __fmul_rn(__fmul_rn(boxes[k*4+2], sx), f);
    out[k*5+3] = __fmul_rn(__fmul_rn(boxes[k*4+3], sy), f);
    out[k*5+4] = __fmul_rn(topScore[k], f);
}

extern "C" void kernel_launch(void* const* d_in, const int* in_sizes, int n_in,
                              void* d_out, int out_size, void* d_ws, size_t ws_size,
                              hipStream_t stream) {
    (void)in_sizes; (void)n_in; (void)out_size; (void)ws_size;
    const float2* cls2   = (const float2*)d_in[0];
    const float* reg     = (const float*)d_in[1];
    const float* anchors = (const float*)d_in[2];
    const int* Hp        = (const int*)d_in[3];
    const int* Wp        = (const int*)d_in[4];
    float* out = (float*)d_out;

    char* ws = (char*)d_ws;
    size_t off = 0;
    auto alloc = [&](size_t bytes) {
        char* p = ws + off;
        off = (off + bytes + 255) & ~(size_t)255;
        return p;
    };
    uint32_t* hist   = (uint32_t*)alloc(BINS * 4);
    uint32_t* ctrs   = (uint32_t*)alloc(64);
    uint64_t* keys   = (uint64_t*)alloc((size_t)CAP * 8);
    uint32_t* order  = (uint32_t*)alloc(KSEL * 4);
    float* topScore  = (float*)alloc(KSEL * 4);
    float* boxes     = (float*)alloc(KSEL * 4 * 4);
    float* areas     = (float*)alloc(KSEL * 4);
    unsigned long long* rowmask   = (unsigned long long*)alloc((size_t)KSEL * 64 * 8);
    unsigned long long* keepWords = (unsigned long long*)alloc(64 * 8);

    k_init<<<16, 256, 0, stream>>>(hist, ctrs, order, topScore);
    k_hist<<<3072, 256, 0, stream>>>(cls2, hist);
    k_thresh<<<1, 1024, 0, stream>>>(hist, ctrs);
    k_gather<<<3072, 256, 0, stream>>>(cls2, ctrs, keys);
    k_rank<<<CAP / 256, 256, 0, stream>>>(keys, ctrs, order, topScore);
    k_decode<<<KSEL / 256, 256, 0, stream>>>(anchors, reg, order, boxes, areas);
    dim3 mg(64, 64);
    k_mask<<<mg, 64, 0, stream>>>(boxes, areas, rowmask);
    k_reduce<<<1, 64, 0, stream>>>(topScore, rowmask, keepWords);
    k_out<<<KSEL / 256, 256, 0, stream>>>(boxes, topScore, keepWords, Hp, Wp, out);
}

// Round 3
// 444.601 us; speedup vs baseline: 1.2832x; 1.2832x over previous
//
#include <hip/hip_runtime.h>
#include <cstdint>

#define N_TOT 1572864
#define KSEL 4096
#define CAP 8192
#define BINS 4096
#define SCORE_THR 0.5f
#define IOU_THR 0.1f

// ---------------- init: zero hist/counters/sorted arrays ----------------
__global__ void k_init(uint32_t* hist, uint32_t* ctrs, uint32_t* order, float* topScore) {
    int i = blockIdx.x * blockDim.x + threadIdx.x;
    if (i < BINS) hist[i] = 0;
    if (i < 16) ctrs[i] = 0;
    if (i < KSEL) { order[i] = 0; topScore[i] = 0.0f; }
}

// ---------------- histogram over score bits (scores in (0.5,1)) ----------------
__global__ void k_hist(const float2* __restrict__ cls2, uint32_t* __restrict__ hist) {
    int i = blockIdx.x * blockDim.x + threadIdx.x;
    int stride = gridDim.x * blockDim.x;
    for (; i < N_TOT; i += stride) {
        float s = cls2[i].y;
        if (s > SCORE_THR) {
            uint32_t b = __float_as_uint(s);
            uint32_t bin = (b - 0x3F000000u) >> 11;
            if (bin >= BINS) bin = BINS - 1;
            atomicAdd(&hist[bin], 1u);
        }
    }
}

// ---------------- find cutoff bin T: largest b with suffix(b) >= K ----------------
__global__ void k_thresh(const uint32_t* __restrict__ hist, uint32_t* __restrict__ ctrs) {
    __shared__ uint32_t s_suf[1024];
    int t = threadIdx.x;
    uint32_t l0 = hist[t*4+0], l1 = hist[t*4+1], l2 = hist[t*4+2], l3 = hist[t*4+3];
    s_suf[t] = l0 + l1 + l2 + l3;
    __syncthreads();
    for (int off = 1; off < 1024; off <<= 1) {
        uint32_t v = (t + off < 1024) ? s_suf[t + off] : 0u;
        __syncthreads();
        s_suf[t] += v;
        __syncthreads();
    }
    uint32_t snext = (t < 1023) ? s_suf[t + 1] : 0u;
    uint32_t suf3 = snext + l3;
    uint32_t suf2 = suf3 + l2;
    uint32_t suf1 = suf2 + l1;
    uint32_t suf0 = suf1 + l0;
    uint32_t sufs[5] = {suf0, suf1, suf2, suf3, snext};
    #pragma unroll
    for (int q = 0; q < 4; q++) {
        if (sufs[q] >= KSEL && sufs[q+1] < KSEL) ctrs[1] = (uint32_t)(t*4 + q);
    }
    if (t == 0 && s_suf[0] < KSEL) ctrs[1] = 0;  // fewer than K candidates
}

// ---------------- gather candidates with bin >= T as sortable 64-bit keys ----------------
__global__ void k_gather(const float2* __restrict__ cls2, uint32_t* __restrict__ ctrs,
                         uint64_t* __restrict__ keys) {
    uint32_t T = ctrs[1];
    uint32_t basebits = 0x3F000000u + (T << 11);
    int i = blockIdx.x * blockDim.x + threadIdx.x;
    int stride = gridDim.x * blockDim.x;
    for (; i < N_TOT; i += stride) {
        float s = cls2[i].y;
        if (s > SCORE_THR) {
            uint32_t b = __float_as_uint(s);
            if (b >= basebits) {
                uint32_t pos = atomicAdd(&ctrs[0], 1u);
                if (pos < CAP) keys[pos] = ((uint64_t)b << 32) | (uint32_t)(~(uint32_t)i);
            }
        }
    }
}

// ---------------- exact rank sort (score desc, idx asc); keys are unique ----------------
__global__ void k_rank(const uint64_t* __restrict__ keys, const uint32_t* __restrict__ ctrs,
                       uint32_t* __restrict__ order, float* __restrict__ topScore) {
    __shared__ uint64_t s_keys[256];
    uint32_t M = ctrs[0]; if (M > CAP) M = CAP;
    int j = blockIdx.x * blockDim.x + threadIdx.x;
    uint64_t myKey = (j < (int)M) ? keys[j] : 0ull;
    uint32_t rank = 0;
    for (uint32_t base = 0; base < M; base += 256) {
        uint32_t idx = base + threadIdx.x;
        s_keys[threadIdx.x] = (idx < M) ? keys[idx] : 0ull;
        __syncthreads();
        uint32_t lim = min(256u, M - base);
        for (uint32_t q = 0; q < lim; q++)
            rank += (s_keys[q] > myKey) ? 1u : 0u;
        __syncthreads();
    }
    if (j < (int)M && rank < KSEL) {
        uint32_t bits = (uint32_t)(myKey >> 32);
        uint32_t srcIdx = ~((uint32_t)(myKey & 0xFFFFFFFFull));
        order[rank] = srcIdx;
        topScore[rank] = __uint_as_float(bits);
    }
}

// ---------------- decode+clip the K winners (mimic numpy f32 rounding; no FMA) ----------------
__global__ void k_decode(const float* __restrict__ anchors, const float* __restrict__ reg,
                         const uint32_t* __restrict__ order, float* __restrict__ boxes,
                         float* __restrict__ areas) {
    int k = blockIdx.x * blockDim.x + threadIdx.x;
    if (k >= KSEL) return;
    uint32_t idx = order[k];
    float a0 = anchors[idx*4+0], a1 = anchors[idx*4+1], a2 = anchors[idx*4+2], a3 = anchors[idx*4+3];
    float d0 = __fmul_rn(reg[idx*4+0], 0.1f);
    float d1 = __fmul_rn(reg[idx*4+1], 0.1f);
    float d2 = __fmul_rn(reg[idx*4+2], 0.2f);
    float d3 = __fmul_rn(reg[idx*4+3], 0.2f);
    float w  = __fsub_rn(a2, a0);
    float h  = __fsub_rn(a3, a1);
    float cx = __fadd_rn(a0, __fmul_rn(0.5f, w));
    float cy = __fadd_rn(a1, __fmul_rn(0.5f, h));
    float pcx = __fadd_rn(cx, __fmul_rn(d0, w));
    float pcy = __fadd_rn(cy, __fmul_rn(d1, h));
    float pw = __fmul_rn((float)exp((double)d2), w);
    float ph = __fmul_rn((float)exp((double)d3), h);
    float x0 = __fsub_rn(pcx, __fmul_rn(0.5f, pw));
    float y0 = __fsub_rn(pcy, __fmul_rn(0.5f, ph));
    float x1 = __fadd_rn(pcx, __fmul_rn(0.5f, pw));
    float y1 = __fadd_rn(pcy, __fmul_rn(0.5f, ph));
    x0 = fminf(fmaxf(x0, 0.0f), 1024.0f);
    y0 = fminf(fmaxf(y0, 0.0f), 1024.0f);
    x1 = fminf(fmaxf(x1, 0.0f), 1024.0f);
    y1 = fminf(fmaxf(y1, 0.0f), 1024.0f);
    boxes[k*4+0] = x0; boxes[k*4+1] = y0; boxes[k*4+2] = x1; boxes[k*4+3] = y1;
    areas[k] = __fmul_rn(__fsub_rn(x1, x0), __fsub_rn(y1, y0));
}

// ---------------- pairwise suppression bitmask; lower-triangle blocks write 0 ----------------
__global__ void k_mask(const float* __restrict__ boxes, const float* __restrict__ areas,
                       unsigned long long* __restrict__ rowmask) {
    int bi = blockIdx.y, bj = blockIdx.x;
    int t = threadIdx.x;
    if (bj < bi) {  // zero-fill so k_reduce needs no word guard
        rowmask[(size_t)(bi*64 + t)*64 + bj] = 0ull;
        return;
    }
    __shared__ float s_box[64][4];
    __shared__ float s_area[64];
    int r0 = bi*64 + t;
    s_box[t][0] = boxes[r0*4+0];
    s_box[t][1] = boxes[r0*4+1];
    s_box[t][2] = boxes[r0*4+2];
    s_box[t][3] = boxes[r0*4+3];
    s_area[t] = areas[r0];
    __syncthreads();
    int j = bj*64 + t;
    float jx0 = boxes[j*4+0], jy0 = boxes[j*4+1], jx1 = boxes[j*4+2], jy1 = boxes[j*4+3];
    float ja = areas[j];
    unsigned long long myword = 0ull;
    #pragma unroll 4
    for (int r = 0; r < 64; r++) {
        int i = bi*64 + r;
        float w = __fsub_rn(fminf(s_box[r][2], jx1), fmaxf(s_box[r][0], jx0));
        float h = __fsub_rn(fminf(s_box[r][3], jy1), fmaxf(s_box[r][1], jy0));
        w = fmaxf(w, 0.0f); h = fmaxf(h, 0.0f);
        float inter = __fmul_rn(w, h);
        float denom = __fadd_rn(__fsub_rn(__fadd_rn(s_area[r], ja), inter), 1e-8f);
        float iou = __fdiv_rn(inter, denom);
        bool sup = (iou > IOU_THR) && (j > i);
        unsigned long long b = __ballot(sup);
        if (t == r) myword = b;
    }
    rowmask[(size_t)(bi*64 + t)*64 + bj] = myword;
}

// ---------------- sequential greedy NMS reduce ----------------
// 1 wave; lane w owns keep word w. Chain uses v_readlane (uniform lane idx),
// 16-deep rolling register prefetch keeps loads off the critical path.
__global__ void k_reduce(const float* __restrict__ topScore,
                         const unsigned long long* __restrict__ rowmask,
                         unsigned long long* __restrict__ keepWords) {
    int w = threadIdx.x;  // 0..63
    unsigned long long keep = 0ull;
    #pragma unroll
    for (int c = 0; c < 64; c += 4) {
        float4 s4 = *reinterpret_cast<const float4*>(&topScore[w*64 + c]);
        keep |= ((unsigned long long)(s4.x > 0.0f) << (c+0))
             |  ((unsigned long long)(s4.y > 0.0f) << (c+1))
             |  ((unsigned long long)(s4.z > 0.0f) << (c+2))
             |  ((unsigned long long)(s4.w > 0.0f) << (c+3));
    }
    uint32_t keep_lo = (uint32_t)keep;
    uint32_t keep_hi = (uint32_t)(keep >> 32);

    const int D = 16;
    unsigned long long buf[D];
    #pragma unroll
    for (int u = 0; u < D; u++) buf[u] = rowmask[(size_t)u*64 + w];

    for (int ib = 0; ib < KSEL; ib += D) {
        #pragma unroll
        for (int u = 0; u < D; u++) {
            int i = ib + u;
            unsigned long long cur = buf[u];
            int nx = i + D; nx = (nx < KSEL) ? nx : (KSEL - 1);
            buf[u] = rowmask[(size_t)nx*64 + w];     // prefetch, independent of chain
            int b = i >> 6;
            uint32_t rl = __builtin_amdgcn_readlane((int)keep_lo, b);
            uint32_t rh = __builtin_amdgcn_readlane((int)keep_hi, b);
            unsigned long long kw = ((unsigned long long)rh << 32) | rl;
            bool alive = (kw >> (i & 63)) & 1ull;
            unsigned long long m = alive ? cur : 0ull;  // lower words are zero rows
            keep_lo &= ~(uint32_t)m;
            keep_hi &= ~(uint32_t)(m >> 32);
        }
    }
    keepWords[w] = ((unsigned long long)keep_hi << 32) | keep_lo;
}

// ---------------- final output: boxes*scale*keep, score*keep ----------------
__global__ void k_out(const float* __restrict__ boxes, const float* __restrict__ topScore,
                      const unsigned long long* __restrict__ keepWords,
                      const int* __restrict__ Hp, const int* __restrict__ Wp,
                      float* __restrict__ out) {
    int k = blockIdx.x * blockDim.x + threadIdx.x;
    if (k >= KSEL) return;
    float sx = (float)((double)Wp[0] / 1024.0);
    float sy = (float)((double)Hp[0] / 1024.0);
    float f = ((keepWords[k >> 6] >> (k & 63)) & 1ull) ? 1.0f : 0.0f;
    out[k*5+0] = __fmul_rn(__fmul_rn(boxes[k*4+0], sx), f);
    out[k*5+1] = __fmul_rn(__fmul_rn(boxes[k*4+1], sy), f);
    out[k*5+2] = __fmul_rn(__fmul_rn(boxes[k*4+2], sx), f);
    out[k*5+3] = __fmul_rn(__fmul_rn(boxes[k*4+3], sy), f);
    out[k*5+4] = __fmul_rn(topScore[k], f);
}

extern "C" void kernel_launch(void* const* d_in, const int* in_sizes, int n_in,
                              void* d_out, int out_size, void* d_ws, size_t ws_size,
                              hipStream_t stream) {
    (void)in_sizes; (void)n_in; (void)out_size; (void)ws_size;
    const float2* cls2   = (const float2*)d_in[0];
    const float* reg     = (const float*)d_in[1];
    const float* anchors = (const float*)d_in[2];
    const int* Hp        = (const int*)d_in[3];
    const int* Wp        = (const int*)d_in[4];
    float* out = (float*)d_out;

    char* ws = (char*)d_ws;
    size_t off = 0;
    auto alloc = [&](size_t bytes) {
        char* p = ws + off;
        off = (off + bytes + 255) & ~(size_t)255;
        return p;
    };
    uint32_t* hist   = (uint32_t*)alloc(BINS * 4);
    uint32_t* ctrs   = (uint32_t*)alloc(64);
    uint64_t* keys   = (uint64_t*)alloc((size_t)CAP * 8);
    uint32_t* order  = (uint32_t*)alloc(KSEL * 4);
    float* topScore  = (float*)alloc(KSEL * 4);
    float* boxes     = (float*)alloc(KSEL * 4 * 4);
    float* areas     = (float*)alloc(KSEL * 4);
    unsigned long long* rowmask   = (unsigned long long*)alloc((size_t)KSEL * 64 * 8);
    unsigned long long* keepWords = (unsigned long long*)alloc(64 * 8);

    k_init<<<16, 256, 0, stream>>>(hist, ctrs, order, topScore);
    k_hist<<<3072, 256, 0, stream>>>(cls2, hist);
    k_thresh<<<1, 1024, 0, stream>>>(hist, ctrs);
    k_gather<<<3072, 256, 0, stream>>>(cls2, ctrs, keys);
    k_rank<<<CAP / 256, 256, 0, stream>>>(keys, ctrs, order, topScore);
    k_decode<<<KSEL / 256, 256, 0, stream>>>(anchors, reg, order, boxes, areas);
    dim3 mg(64, 64);
    k_mask<<<mg, 64, 0, stream>>>(boxes, areas, rowmask);
    k_reduce<<<1, 64, 0, stream>>>(topScore, rowmask, keepWords);
    k_out<<<KSEL / 256, 256, 0, stream>>>(boxes, topScore, keepWords, Hp, Wp, out);
}

// Round 4
// 412.390 us; speedup vs baseline: 1.3834x; 1.0781x over previous
//
#include <hip/hip_runtime.h>
#include <cstdint>

#define N_TOT 1572864
#define KSEL 4096
#define CAP 8192
#define BINS 4096
#define SCORE_THR 0.5f
#define IOU_THR 0.1f
#define HIST_BLOCKS 3072

__device__ inline uint64_t readlane64(uint64_t v, int lane) {
    uint32_t lo = (uint32_t)__builtin_amdgcn_readlane((int)(uint32_t)v, lane);
    uint32_t hi = (uint32_t)__builtin_amdgcn_readlane((int)(uint32_t)(v >> 32), lane);
    return ((uint64_t)hi << 32) | lo;
}

// ---------------- init: zero hist/counters/topScore ----------------
__global__ void k_init(uint32_t* hist, uint32_t* ctrs, float* topScore) {
    int i = blockIdx.x * blockDim.x + threadIdx.x;
    if (i < BINS) hist[i] = 0;
    if (i < 16) ctrs[i] = 0;
    if (i < KSEL) topScore[i] = 0.0f;
}

// ---------------- histogram + (last block) threshold scan ----------------
__global__ void k_hist(const float2* __restrict__ cls2, uint32_t* __restrict__ hist,
                       uint32_t* __restrict__ ctrs) {
    int i = blockIdx.x * blockDim.x + threadIdx.x;
    int stride = gridDim.x * blockDim.x;
    for (; i < N_TOT; i += stride) {
        float s = cls2[i].y;
        if (s > SCORE_THR) {
            uint32_t b = __float_as_uint(s);
            uint32_t bin = (b - 0x3F000000u) >> 11;
            if (bin >= BINS) bin = BINS - 1;
            atomicAdd(&hist[bin], 1u);
        }
    }
    // arrival counter; last block computes the cutoff bin
    __threadfence();
    __syncthreads();
    __shared__ uint32_t s_last;
    if (threadIdx.x == 0)
        s_last = (atomicAdd(&ctrs[2], 1u) == (uint32_t)gridDim.x - 1) ? 1u : 0u;
    __syncthreads();
    if (!s_last) return;
    __threadfence();  // acquire: see all blocks' hist atomics

    __shared__ uint32_t s_part[256];
    int t = threadIdx.x;  // 256 threads, 16 bins each
    uint32_t loc[16];
    uint32_t sum = 0;
    #pragma unroll
    for (int q = 0; q < 16; q++) {
        loc[q] = atomicAdd(&hist[t * 16 + q], 0u);  // coherent read
        sum += loc[q];
    }
    s_part[t] = sum;
    __syncthreads();
    for (int off = 1; off < 256; off <<= 1) {
        uint32_t v = (t + off < 256) ? s_part[t + off] : 0u;
        __syncthreads();
        s_part[t] += v;
        __syncthreads();
    }
    uint32_t after = (t + 1 < 256) ? s_part[t + 1] : 0u;
    uint32_t sufq[17];
    sufq[16] = after;
    #pragma unroll
    for (int q = 15; q >= 0; q--) sufq[q] = sufq[q + 1] + loc[q];
    #pragma unroll
    for (int q = 0; q < 16; q++)
        if (sufq[q] >= KSEL && sufq[q + 1] < KSEL) ctrs[1] = (uint32_t)(t * 16 + q);
    if (t == 0 && s_part[0] < KSEL) ctrs[1] = 0;
}

// ---------------- gather candidates with bin >= T as sortable 64-bit keys ----------------
__global__ void k_gather(const float2* __restrict__ cls2, uint32_t* __restrict__ ctrs,
                         uint64_t* __restrict__ keys) {
    uint32_t T = ctrs[1];
    uint32_t basebits = 0x3F000000u + (T << 11);
    int i = blockIdx.x * blockDim.x + threadIdx.x;
    int stride = gridDim.x * blockDim.x;
    for (; i < N_TOT; i += stride) {
        float s = cls2[i].y;
        if (s > SCORE_THR) {
            uint32_t b = __float_as_uint(s);
            if (b >= basebits) {
                uint32_t pos = atomicAdd(&ctrs[0], 1u);
                if (pos < CAP) keys[pos] = ((uint64_t)b << 32) | (uint32_t)(~(uint32_t)i);
            }
        }
    }
}

// ---------------- exact rank sort + fused decode (numpy f32 rounding, no FMA) ----------------
__global__ void k_rankdec(const uint64_t* __restrict__ keys, const uint32_t* __restrict__ ctrs,
                          const float* __restrict__ anchors, const float* __restrict__ reg,
                          float* __restrict__ topScore, float* __restrict__ boxes,
                          float* __restrict__ areas) {
    __shared__ uint64_t s_keys[256];
    uint32_t M = ctrs[0]; if (M > CAP) M = CAP;
    int j = blockIdx.x * blockDim.x + threadIdx.x;
    uint64_t myKey = (j < (int)M) ? keys[j] : 0ull;
    uint32_t rank = 0;
    for (uint32_t base = 0; base < M; base += 256) {
        uint32_t idx = base + threadIdx.x;
        s_keys[threadIdx.x] = (idx < M) ? keys[idx] : 0ull;
        __syncthreads();
        uint32_t lim = min(256u, M - base);
        for (uint32_t q = 0; q < lim; q++)
            rank += (s_keys[q] > myKey) ? 1u : 0u;
        __syncthreads();
    }
    if (j < (int)M && rank < KSEL) {
        uint32_t srcIdx = ~((uint32_t)(myKey & 0xFFFFFFFFull));
        topScore[rank] = __uint_as_float((uint32_t)(myKey >> 32));
        float4 a = *reinterpret_cast<const float4*>(&anchors[(size_t)srcIdx * 4]);
        float4 dd = *reinterpret_cast<const float4*>(&reg[(size_t)srcIdx * 4]);
        float d0 = __fmul_rn(dd.x, 0.1f);
        float d1 = __fmul_rn(dd.y, 0.1f);
        float d2 = __fmul_rn(dd.z, 0.2f);
        float d3 = __fmul_rn(dd.w, 0.2f);
        float w  = __fsub_rn(a.z, a.x);
        float h  = __fsub_rn(a.w, a.y);
        float cx = __fadd_rn(a.x, __fmul_rn(0.5f, w));
        float cy = __fadd_rn(a.y, __fmul_rn(0.5f, h));
        float pcx = __fadd_rn(cx, __fmul_rn(d0, w));
        float pcy = __fadd_rn(cy, __fmul_rn(d1, h));
        float pw = __fmul_rn((float)exp((double)d2), w);
        float ph = __fmul_rn((float)exp((double)d3), h);
        float x0 = __fsub_rn(pcx, __fmul_rn(0.5f, pw));
        float y0 = __fsub_rn(pcy, __fmul_rn(0.5f, ph));
        float x1 = __fadd_rn(pcx, __fmul_rn(0.5f, pw));
        float y1 = __fadd_rn(pcy, __fmul_rn(0.5f, ph));
        x0 = fminf(fmaxf(x0, 0.0f), 1024.0f);
        y0 = fminf(fmaxf(y0, 0.0f), 1024.0f);
        x1 = fminf(fmaxf(x1, 0.0f), 1024.0f);
        y1 = fminf(fmaxf(y1, 0.0f), 1024.0f);
        *reinterpret_cast<float4*>(&boxes[(size_t)rank * 4]) = make_float4(x0, y0, x1, y1);
        areas[rank] = __fmul_rn(__fsub_rn(x1, x0), __fsub_rn(y1, y0));
    }
}

// ---------------- pairwise suppression bitmask; lower-triangle blocks write 0 ----------------
__global__ void k_mask(const float* __restrict__ boxes, const float* __restrict__ areas,
                       unsigned long long* __restrict__ rowmask) {
    int bi = blockIdx.y, bj = blockIdx.x;
    int t = threadIdx.x;
    if (bj < bi) {  // zero-fill so reduce can AND rows unguarded
        rowmask[(size_t)(bi * 64 + t) * 64 + bj] = 0ull;
        return;
    }
    __shared__ float s_box[64][4];
    __shared__ float s_area[64];
    int r0 = bi * 64 + t;
    s_box[t][0] = boxes[r0 * 4 + 0];
    s_box[t][1] = boxes[r0 * 4 + 1];
    s_box[t][2] = boxes[r0 * 4 + 2];
    s_box[t][3] = boxes[r0 * 4 + 3];
    s_area[t] = areas[r0];
    __syncthreads();
    int j = bj * 64 + t;
    float jx0 = boxes[j * 4 + 0], jy0 = boxes[j * 4 + 1], jx1 = boxes[j * 4 + 2], jy1 = boxes[j * 4 + 3];
    float ja = areas[j];
    unsigned long long myword = 0ull;
    #pragma unroll 4
    for (int r = 0; r < 64; r++) {
        int i = bi * 64 + r;
        float w = __fsub_rn(fminf(s_box[r][2], jx1), fmaxf(s_box[r][0], jx0));
        float h = __fsub_rn(fminf(s_box[r][3], jy1), fmaxf(s_box[r][1], jy0));
        w = fmaxf(w, 0.0f); h = fmaxf(h, 0.0f);
        float inter = __fmul_rn(w, h);
        float denom = __fadd_rn(__fsub_rn(__fadd_rn(s_area[r], ja), inter), 1e-8f);
        float iou = __fdiv_rn(inter, denom);
        bool sup = (iou > IOU_THR) && (j > i);
        unsigned long long b = __ballot(sup);
        if (t == r) myword = b;
    }
    rowmask[(size_t)(bi * 64 + t) * 64 + bj] = myword;
}

// ---------------- block-diagonal greedy NMS reduce + fused output ----------------
// 1 wave; lane w owns keep word w. Per 64-block: phase 1 resolves the diagonal
// 64x64 in registers (scalar ctz + readlane; acting set == final alive set since
// row i only kills j>i). Phase 2 ORs full rows of alive i's (8 loads/round,
// independent -> one memory latency per round).
__global__ void k_reduce(const float* __restrict__ topScore,
                         const unsigned long long* __restrict__ rowmask,
                         const float* __restrict__ boxes,
                         const int* __restrict__ Hp, const int* __restrict__ Wp,
                         float* __restrict__ out) {
    int w = threadIdx.x;  // 0..63
    uint64_t keep = 0ull;
    #pragma unroll
    for (int c = 0; c < 64; c += 4) {
        float4 s4 = *reinterpret_cast<const float4*>(&topScore[w * 64 + c]);
        keep |= ((uint64_t)(s4.x > 0.0f) << (c + 0))
             |  ((uint64_t)(s4.y > 0.0f) << (c + 1))
             |  ((uint64_t)(s4.z > 0.0f) << (c + 2))
             |  ((uint64_t)(s4.w > 0.0f) << (c + 3));
    }

    // diag for block b: lane i holds row (b*64+i)'s word b. Prefetch 2 ahead.
    uint64_t dg0 = rowmask[(size_t)(0 * 64 + w) * 64 + 0];
    uint64_t dg1 = rowmask[(size_t)(1 * 64 + w) * 64 + 1];

    for (int b = 0; b < 64; b++) {
        uint64_t diag = dg0;
        dg0 = dg1;
        int nb = (b + 2 < 64) ? (b + 2) : 63;
        dg1 = rowmask[(size_t)(nb * 64 + w) * 64 + nb];

        // phase 1: scalar within-block suppression
        uint32_t klo = (uint32_t)__builtin_amdgcn_readlane((int)(uint32_t)keep, b);
        uint32_t khi = (uint32_t)__builtin_amdgcn_readlane((int)(uint32_t)(keep >> 32), b);
        uint64_t kw = ((uint64_t)khi << 32) | klo;
        uint64_t rem = kw;
        while (rem) {
            int i = __builtin_ctzll(rem);
            rem &= rem - 1;                      // bit i stays alive in kw (row i bit i == 0)
            uint64_t row = readlane64(diag, i);
            kw &= ~row;
            rem &= ~row;
        }

        // phase 2: OR full rows of final-alive i's into acc (8-batched loads)
        uint64_t acc = 0ull;
        uint64_t rem2 = kw;
        const unsigned long long* base = rowmask + (size_t)(b * 64) * 64 + w;
        while (rem2) {
            int i0 = __builtin_ctzll(rem2); uint64_t r = rem2 & (rem2 - 1);
            int i1 = r ? __builtin_ctzll(r) : i0; r = r ? (r & (r - 1)) : r;
            int i2 = r ? __builtin_ctzll(r) : i0; r = r ? (r & (r - 1)) : r;
            int i3 = r ? __builtin_ctzll(r) : i0; r = r ? (r & (r - 1)) : r;
            int i4 = r ? __builtin_ctzll(r) : i0; r = r ? (r & (r - 1)) : r;
            int i5 = r ? __builtin_ctzll(r) : i0; r = r ? (r & (r - 1)) : r;
            int i6 = r ? __builtin_ctzll(r) : i0; r = r ? (r & (r - 1)) : r;
            int i7 = r ? __builtin_ctzll(r) : i0; r = r ? (r & (r - 1)) : r;
            rem2 = r;
            uint64_t r0 = base[(size_t)i0 * 64];
            uint64_t r1 = base[(size_t)i1 * 64];
            uint64_t r2 = base[(size_t)i2 * 64];
            uint64_t r3 = base[(size_t)i3 * 64];
            uint64_t r4 = base[(size_t)i4 * 64];
            uint64_t r5 = base[(size_t)i5 * 64];
            uint64_t r6 = base[(size_t)i6 * 64];
            uint64_t r7 = base[(size_t)i7 * 64];
            acc |= (r0 | r1) | (r2 | r3) | ((r4 | r5) | (r6 | r7));
        }
        keep &= ~acc;   // lanes < b: rows' lower words are zero; lane b: reproduces kw
    }

    // fused output: lane w owns rows [w*64, w*64+64)
    float sx = (float)((double)Wp[0] / 1024.0);
    float sy = (float)((double)Hp[0] / 1024.0);
    for (int c = 0; c < 64; c++) {
        int k = w * 64 + c;
        float f = ((keep >> c) & 1ull) ? 1.0f : 0.0f;
        float4 bx = *reinterpret_cast<const float4*>(&boxes[(size_t)k * 4]);
        out[k * 5 + 0] = __fmul_rn(__fmul_rn(bx.x, sx), f);
        out[k * 5 + 1] = __fmul_rn(__fmul_rn(bx.y, sy), f);
        out[k * 5 + 2] = __fmul_rn(__fmul_rn(bx.z, sx), f);
        out[k * 5 + 3] = __fmul_rn(__fmul_rn(bx.w, sy), f);
        out[k * 5 + 4] = __fmul_rn(topScore[k], f);
    }
}

extern "C" void kernel_launch(void* const* d_in, const int* in_sizes, int n_in,
                              void* d_out, int out_size, void* d_ws, size_t ws_size,
                              hipStream_t stream) {
    (void)in_sizes; (void)n_in; (void)out_size; (void)ws_size;
    const float2* cls2   = (const float2*)d_in[0];
    const float* reg     = (const float*)d_in[1];
    const float* anchors = (const float*)d_in[2];
    const int* Hp        = (const int*)d_in[3];
    const int* Wp        = (const int*)d_in[4];
    float* out = (float*)d_out;

    char* ws = (char*)d_ws;
    size_t off = 0;
    auto alloc = [&](size_t bytes) {
        char* p = ws + off;
        off = (off + bytes + 255) & ~(size_t)255;
        return p;
    };
    uint32_t* hist   = (uint32_t*)alloc(BINS * 4);
    uint32_t* ctrs   = (uint32_t*)alloc(64);
    uint64_t* keys   = (uint64_t*)alloc((size_t)CAP * 8);
    float* topScore  = (float*)alloc(KSEL * 4);
    float* boxes     = (float*)alloc(KSEL * 4 * 4);
    float* areas     = (float*)alloc(KSEL * 4);
    unsigned long long* rowmask = (unsigned long long*)alloc((size_t)KSEL * 64 * 8);

    k_init<<<16, 256, 0, stream>>>(hist, ctrs, topScore);
    k_hist<<<HIST_BLOCKS, 256, 0, stream>>>(cls2, hist, ctrs);
    k_gather<<<3072, 256, 0, stream>>>(cls2, ctrs, keys);
    k_rankdec<<<CAP / 256, 256, 0, stream>>>(keys, ctrs, anchors, reg, topScore, boxes, areas);
    dim3 mg(64, 64);
    k_mask<<<mg, 64, 0, stream>>>(boxes, areas, rowmask);
    k_reduce<<<1, 64, 0, stream>>>(topScore, rowmask, boxes, Hp, Wp, out);
}

// Round 5
// 231.807 us; speedup vs baseline: 2.4611x; 1.7790x over previous
//
#include <hip/hip_runtime.h>
#include <cstdint>

#define N_TOT 1572864
#define KSEL 4096
#define CAP 8192
#define BINS 4096
#define SCORE_THR 0.5f
#define IOU_THR 0.1f
#define STREAM_BLOCKS 512
#define STAGE 512

__device__ inline uint64_t readlane64(uint64_t v, int lane) {
    uint32_t lo = (uint32_t)__builtin_amdgcn_readlane((int)(uint32_t)v, lane);
    uint32_t hi = (uint32_t)__builtin_amdgcn_readlane((int)(uint32_t)(v >> 32), lane);
    return ((uint64_t)hi << 32) | lo;
}

// ---------------- init: zero hist/counters/topScore ----------------
__global__ void k_init(uint32_t* hist, uint32_t* ctrs, float* topScore) {
    int i = blockIdx.x * blockDim.x + threadIdx.x;
    if (i < BINS) hist[i] = 0;
    if (i < 16) ctrs[i] = 0;
    if (i < KSEL) topScore[i] = 0.0f;
}

// ---------------- histogram over score bits (scores in (0.5,1)), float4 stream ----------------
__global__ void k_hist(const float4* __restrict__ cls4, uint32_t* __restrict__ hist) {
    int i = blockIdx.x * blockDim.x + threadIdx.x;
    int stride = gridDim.x * blockDim.x;
    for (; i < N_TOT / 2; i += stride) {
        float4 c = cls4[i];
        if (c.y > SCORE_THR) {
            uint32_t bin = (__float_as_uint(c.y) - 0x3F000000u) >> 11;
            if (bin >= BINS) bin = BINS - 1;
            atomicAdd(&hist[bin], 1u);
        }
        if (c.w > SCORE_THR) {
            uint32_t bin = (__float_as_uint(c.w) - 0x3F000000u) >> 11;
            if (bin >= BINS) bin = BINS - 1;
            atomicAdd(&hist[bin], 1u);
        }
    }
}

// ---------------- find cutoff bin T: largest b with suffix(b) >= K ----------------
__global__ void k_thresh(const uint32_t* __restrict__ hist, uint32_t* __restrict__ ctrs) {
    __shared__ uint32_t s_suf[1024];
    int t = threadIdx.x;
    uint32_t l0 = hist[t*4+0], l1 = hist[t*4+1], l2 = hist[t*4+2], l3 = hist[t*4+3];
    s_suf[t] = l0 + l1 + l2 + l3;
    __syncthreads();
    for (int off = 1; off < 1024; off <<= 1) {
        uint32_t v = (t + off < 1024) ? s_suf[t + off] : 0u;
        __syncthreads();
        s_suf[t] += v;
        __syncthreads();
    }
    uint32_t snext = (t < 1023) ? s_suf[t + 1] : 0u;
    uint32_t suf3 = snext + l3;
    uint32_t suf2 = suf3 + l2;
    uint32_t suf1 = suf2 + l1;
    uint32_t suf0 = suf1 + l0;
    uint32_t sufs[5] = {suf0, suf1, suf2, suf3, snext};
    #pragma unroll
    for (int q = 0; q < 4; q++) {
        if (sufs[q] >= KSEL && sufs[q+1] < KSEL) ctrs[1] = (uint32_t)(t*4 + q);
    }
    if (t == 0 && s_suf[0] < KSEL) ctrs[1] = 0;  // fewer than K candidates
}

// ---------------- gather candidates (bin >= T) via LDS staging; 1 global atomic/block ----------------
__global__ void k_gather(const float4* __restrict__ cls4, uint32_t* __restrict__ ctrs,
                         uint64_t* __restrict__ keys) {
    __shared__ uint32_t s_cnt;
    __shared__ uint32_t s_base;
    __shared__ uint64_t s_stage[STAGE];
    if (threadIdx.x == 0) s_cnt = 0;
    __syncthreads();

    uint32_t T = ctrs[1];
    uint32_t basebits = 0x3F000000u + (T << 11);
    int i = blockIdx.x * blockDim.x + threadIdx.x;
    int stride = gridDim.x * blockDim.x;
    for (; i < N_TOT / 2; i += stride) {
        float4 c = cls4[i];
        #pragma unroll
        for (int h = 0; h < 2; h++) {
            float s = h ? c.w : c.y;
            uint32_t idx = 2u * (uint32_t)i + (uint32_t)h;
            if (s > SCORE_THR) {
                uint32_t b = __float_as_uint(s);
                if (b >= basebits) {
                    uint64_t key = ((uint64_t)b << 32) | (uint32_t)(~idx);
                    uint32_t p = atomicAdd(&s_cnt, 1u);
                    if (p < STAGE) s_stage[p] = key;
                    else {  // overflow: rare fallback, correctness-preserving
                        uint32_t g = atomicAdd(&ctrs[0], 1u);
                        if (g < CAP) keys[g] = key;
                    }
                }
            }
        }
    }
    __syncthreads();
    uint32_t n = s_cnt < STAGE ? s_cnt : STAGE;
    if (threadIdx.x == 0 && n > 0) s_base = atomicAdd(&ctrs[0], n);
    __syncthreads();
    for (uint32_t q = threadIdx.x; q < n; q += blockDim.x) {
        uint32_t g = s_base + q;
        if (g < CAP) keys[g] = s_stage[q];
    }
}

// ---------------- exact rank sort + fused decode (numpy f32 rounding, no FMA) ----------------
__global__ void k_rankdec(const uint64_t* __restrict__ keys, const uint32_t* __restrict__ ctrs,
                          const float* __restrict__ anchors, const float* __restrict__ reg,
                          float* __restrict__ topScore, float* __restrict__ boxes,
                          float* __restrict__ areas) {
    __shared__ uint64_t s_keys[256];
    uint32_t M = ctrs[0]; if (M > CAP) M = CAP;
    int j = blockIdx.x * blockDim.x + threadIdx.x;
    uint64_t myKey = (j < (int)M) ? keys[j] : 0ull;
    uint32_t rank = 0;
    for (uint32_t base = 0; base < M; base += 256) {
        uint32_t idx = base + threadIdx.x;
        s_keys[threadIdx.x] = (idx < M) ? keys[idx] : 0ull;
        __syncthreads();
        uint32_t lim = min(256u, M - base);
        for (uint32_t q = 0; q < lim; q++)
            rank += (s_keys[q] > myKey) ? 1u : 0u;
        __syncthreads();
    }
    if (j < (int)M && rank < KSEL) {
        uint32_t srcIdx = ~((uint32_t)(myKey & 0xFFFFFFFFull));
        topScore[rank] = __uint_as_float((uint32_t)(myKey >> 32));
        float4 a = *reinterpret_cast<const float4*>(&anchors[(size_t)srcIdx * 4]);
        float4 dd = *reinterpret_cast<const float4*>(&reg[(size_t)srcIdx * 4]);
        float d0 = __fmul_rn(dd.x, 0.1f);
        float d1 = __fmul_rn(dd.y, 0.1f);
        float d2 = __fmul_rn(dd.z, 0.2f);
        float d3 = __fmul_rn(dd.w, 0.2f);
        float w  = __fsub_rn(a.z, a.x);
        float h  = __fsub_rn(a.w, a.y);
        float cx = __fadd_rn(a.x, __fmul_rn(0.5f, w));
        float cy = __fadd_rn(a.y, __fmul_rn(0.5f, h));
        float pcx = __fadd_rn(cx, __fmul_rn(d0, w));
        float pcy = __fadd_rn(cy, __fmul_rn(d1, h));
        float pw = __fmul_rn((float)exp((double)d2), w);
        float ph = __fmul_rn((float)exp((double)d3), h);
        float x0 = __fsub_rn(pcx, __fmul_rn(0.5f, pw));
        float y0 = __fsub_rn(pcy, __fmul_rn(0.5f, ph));
        float x1 = __fadd_rn(pcx, __fmul_rn(0.5f, pw));
        float y1 = __fadd_rn(pcy, __fmul_rn(0.5f, ph));
        x0 = fminf(fmaxf(x0, 0.0f), 1024.0f);
        y0 = fminf(fmaxf(y0, 0.0f), 1024.0f);
        x1 = fminf(fmaxf(x1, 0.0f), 1024.0f);
        y1 = fminf(fmaxf(y1, 0.0f), 1024.0f);
        *reinterpret_cast<float4*>(&boxes[(size_t)rank * 4]) = make_float4(x0, y0, x1, y1);
        areas[rank] = __fmul_rn(__fsub_rn(x1, x0), __fsub_rn(y1, y0));
    }
}

// ---------------- pairwise suppression bitmask; lower-triangle blocks write 0 ----------------
__global__ void k_mask(const float* __restrict__ boxes, const float* __restrict__ areas,
                       unsigned long long* __restrict__ rowmask) {
    int bi = blockIdx.y, bj = blockIdx.x;
    int t = threadIdx.x;
    if (bj < bi) {  // zero-fill so reduce can AND rows unguarded
        rowmask[(size_t)(bi * 64 + t) * 64 + bj] = 0ull;
        return;
    }
    __shared__ float s_box[64][4];
    __shared__ float s_area[64];
    int r0 = bi * 64 + t;
    s_box[t][0] = boxes[r0 * 4 + 0];
    s_box[t][1] = boxes[r0 * 4 + 1];
    s_box[t][2] = boxes[r0 * 4 + 2];
    s_box[t][3] = boxes[r0 * 4 + 3];
    s_area[t] = areas[r0];
    __syncthreads();
    int j = bj * 64 + t;
    float jx0 = boxes[j * 4 + 0], jy0 = boxes[j * 4 + 1], jx1 = boxes[j * 4 + 2], jy1 = boxes[j * 4 + 3];
    float ja = areas[j];
    unsigned long long myword = 0ull;
    #pragma unroll 4
    for (int r = 0; r < 64; r++) {
        int i = bi * 64 + r;
        float w = __fsub_rn(fminf(s_box[r][2], jx1), fmaxf(s_box[r][0], jx0));
        float h = __fsub_rn(fminf(s_box[r][3], jy1), fmaxf(s_box[r][1], jy0));
        w = fmaxf(w, 0.0f); h = fmaxf(h, 0.0f);
        float inter = __fmul_rn(w, h);
        float denom = __fadd_rn(__fsub_rn(__fadd_rn(s_area[r], ja), inter), 1e-8f);
        float iou = __fdiv_rn(inter, denom);
        bool sup = (iou > IOU_THR) && (j > i);
        unsigned long long b = __ballot(sup);
        if (t == r) myword = b;
    }
    rowmask[(size_t)(bi * 64 + t) * 64 + bj] = myword;
}

// ---------------- block-diagonal greedy NMS reduce + fused output ----------------
__global__ void k_reduce(const float* __restrict__ topScore,
                         const unsigned long long* __restrict__ rowmask,
                         const float* __restrict__ boxes,
                         const int* __restrict__ Hp, const int* __restrict__ Wp,
                         float* __restrict__ out) {
    int w = threadIdx.x;  // 0..63
    uint64_t keep = 0ull;
    #pragma unroll
    for (int c = 0; c < 64; c += 4) {
        float4 s4 = *reinterpret_cast<const float4*>(&topScore[w * 64 + c]);
        keep |= ((uint64_t)(s4.x > 0.0f) << (c + 0))
             |  ((uint64_t)(s4.y > 0.0f) << (c + 1))
             |  ((uint64_t)(s4.z > 0.0f) << (c + 2))
             |  ((uint64_t)(s4.w > 0.0f) << (c + 3));
    }

    uint64_t dg0 = rowmask[(size_t)(0 * 64 + w) * 64 + 0];
    uint64_t dg1 = rowmask[(size_t)(1 * 64 + w) * 64 + 1];

    for (int b = 0; b < 64; b++) {
        uint64_t diag = dg0;
        dg0 = dg1;
        int nb = (b + 2 < 64) ? (b + 2) : 63;
        dg1 = rowmask[(size_t)(nb * 64 + w) * 64 + nb];

        // phase 1: scalar within-block suppression (acting set == final alive set)
        uint32_t klo = (uint32_t)__builtin_amdgcn_readlane((int)(uint32_t)keep, b);
        uint32_t khi = (uint32_t)__builtin_amdgcn_readlane((int)(uint32_t)(keep >> 32), b);
        uint64_t kw = ((uint64_t)khi << 32) | klo;
        uint64_t rem = kw;
        while (rem) {
            int i = __builtin_ctzll(rem);
            rem &= rem - 1;
            uint64_t row = readlane64(diag, i);
            kw &= ~row;
            rem &= ~row;
        }

        // phase 2: OR full rows of final-alive i's (8-batched independent loads)
        uint64_t acc = 0ull;
        uint64_t rem2 = kw;
        const unsigned long long* base = rowmask + (size_t)(b * 64) * 64 + w;
        while (rem2) {
            int i0 = __builtin_ctzll(rem2); uint64_t r = rem2 & (rem2 - 1);
            int i1 = r ? __builtin_ctzll(r) : i0; r = r ? (r & (r - 1)) : r;
            int i2 = r ? __builtin_ctzll(r) : i0; r = r ? (r & (r - 1)) : r;
            int i3 = r ? __builtin_ctzll(r) : i0; r = r ? (r & (r - 1)) : r;
            int i4 = r ? __builtin_ctzll(r) : i0; r = r ? (r & (r - 1)) : r;
            int i5 = r ? __builtin_ctzll(r) : i0; r = r ? (r & (r - 1)) : r;
            int i6 = r ? __builtin_ctzll(r) : i0; r = r ? (r & (r - 1)) : r;
            int i7 = r ? __builtin_ctzll(r) : i0; r = r ? (r & (r - 1)) : r;
            rem2 = r;
            uint64_t r0 = base[(size_t)i0 * 64];
            uint64_t r1 = base[(size_t)i1 * 64];
            uint64_t r2 = base[(size_t)i2 * 64];
            uint64_t r3 = base[(size_t)i3 * 64];
            uint64_t r4 = base[(size_t)i4 * 64];
            uint64_t r5 = base[(size_t)i5 * 64];
            uint64_t r6 = base[(size_t)i6 * 64];
            uint64_t r7 = base[(size_t)i7 * 64];
            acc |= (r0 | r1) | (r2 | r3) | ((r4 | r5) | (r6 | r7));
        }
        keep &= ~acc;
    }

    // fused output: lane w owns rows [w*64, w*64+64)
    float sx = (float)((double)Wp[0] / 1024.0);
    float sy = (float)((double)Hp[0] / 1024.0);
    for (int c = 0; c < 64; c++) {
        int k = w * 64 + c;
        float f = ((keep >> c) & 1ull) ? 1.0f : 0.0f;
        float4 bx = *reinterpret_cast<const float4*>(&boxes[(size_t)k * 4]);
        out[k * 5 + 0] = __fmul_rn(__fmul_rn(bx.x, sx), f);
        out[k * 5 + 1] = __fmul_rn(__fmul_rn(bx.y, sy), f);
        out[k * 5 + 2] = __fmul_rn(__fmul_rn(bx.z, sx), f);
        out[k * 5 + 3] = __fmul_rn(__fmul_rn(bx.w, sy), f);
        out[k * 5 + 4] = __fmul_rn(topScore[k], f);
    }
}

extern "C" void kernel_launch(void* const* d_in, const int* in_sizes, int n_in,
                              void* d_out, int out_size, void* d_ws, size_t ws_size,
                              hipStream_t stream) {
    (void)in_sizes; (void)n_in; (void)out_size; (void)ws_size;
    const float4* cls4   = (const float4*)d_in[0];
    const float* reg     = (const float*)d_in[1];
    const float* anchors = (const float*)d_in[2];
    const int* Hp        = (const int*)d_in[3];
    const int* Wp        = (const int*)d_in[4];
    float* out = (float*)d_out;

    char* ws = (char*)d_ws;
    size_t off = 0;
    auto alloc = [&](size_t bytes) {
        char* p = ws + off;
        off = (off + bytes + 255) & ~(size_t)255;
        return p;
    };
    uint32_t* hist   = (uint32_t*)alloc(BINS * 4);
    uint32_t* ctrs   = (uint32_t*)alloc(64);
    uint64_t* keys   = (uint64_t*)alloc((size_t)CAP * 8);
    float* topScore  = (float*)alloc(KSEL * 4);
    float* boxes     = (float*)alloc(KSEL * 4 * 4);
    float* areas     = (float*)alloc(KSEL * 4);
    unsigned long long* rowmask = (unsigned long long*)alloc((size_t)KSEL * 64 * 8);

    k_init<<<16, 256, 0, stream>>>(hist, ctrs, topScore);
    k_hist<<<STREAM_BLOCKS, 256, 0, stream>>>(cls4, hist);
    k_thresh<<<1, 1024, 0, stream>>>(hist, ctrs);
    k_gather<<<STREAM_BLOCKS, 256, 0, stream>>>(cls4, ctrs, keys);
    k_rankdec<<<CAP / 256, 256, 0, stream>>>(keys, ctrs, anchors, reg, topScore, boxes, areas);
    dim3 mg(64, 64);
    k_mask<<<mg, 64, 0, stream>>>(boxes, areas, rowmask);
    k_reduce<<<1, 64, 0, stream>>>(topScore, rowmask, boxes, Hp, Wp, out);
}